// Round 3
// baseline (15008.261 us; speedup 1.0000x reference)
//
#include <hip/hip_runtime.h>
#include <cstdint>

// Problem constants: D=512, H=2048, T=2048, O=512, 4H=8192.
#define H_DIM 2048
#define H4_DIM 8192
#define T_LEN 2048

typedef unsigned long long u64;

__device__ __forceinline__ float sigmoid_f(float x) {
  return 1.0f / (1.0f + __expf(-x));
}
__device__ __forceinline__ float tanh_f(float x) {
  float ax = fabsf(x);
  float e = __expf(-2.0f * ax);
  float r = (1.0f - e) / (1.0f + e);
  return copysignf(r, x);
}

// ---- persistent LSTM recurrence, weights register-resident, NO barrier ----
// Cross-step exchange: slot[parity][j] = (tag<<32)|bits(h_j), relaxed agent
// 64-bit atomics (LLC-coherent). Parity double-buffer + all-to-all dependence
// makes overwrite-before-read impossible. 0xAAAAAAAA poison never matches
// tags 1..2048 -> no init needed.
//
// Latency engineering (round 3):
//  * xp comes in TRANSPOSED (8192, T): each wave loads its 4 gate rows for 64
//    steps in one coalesced shot, double-buffered one chunk ahead -> xp HBM
//    misses are off the per-step critical path. Per step: 4 shfl broadcasts.
//  * butterfly = allreduce -> ALL lanes compute gates redundantly, c is
//    replicated per-lane (bit-identical); only the publish store is lane 0.
//  * hl is double-buffered -> one __syncthreads per step (write to hl[t&1]
//    at step t is separated from reads at t-2 by the sync at t-1).
__global__ __launch_bounds__(512, 2) void lstm_rec(
    const float* __restrict__ Whh,   // (8192, 2048)
    const float* __restrict__ xpT,   // (8192, T) transposed x-projection+biases
    u64* __restrict__ slots,         // 2 * 2048 tagged h slots
    float* __restrict__ ys,          // (T, 2048) or nullptr
    int T)
{
  __shared__ float hl[2][H_DIM];
  const int g = blockIdx.x;
  const int tid = threadIdx.x;
  const int w = tid >> 6;
  const int l = tid & 63;
  const int j = g * 8 + w;

  // one-time weight load (each element read exactly once grid-wide)
  float wreg[128];
  #pragma unroll
  for (int q = 0; q < 4; ++q) {
    const float* wr = Whh + (size_t)(j + q * H_DIM) * H_DIM + l * 4;
    #pragma unroll
    for (int k = 0; k < 8; ++k) {
      float4 v = *(const float4*)(wr + 256 * k);
      wreg[q * 32 + k * 4 + 0] = v.x;
      wreg[q * 32 + k * 4 + 1] = v.y;
      wreg[q * 32 + k * 4 + 2] = v.z;
      wreg[q * 32 + k * 4 + 3] = v.w;
    }
  }

  // xp rows for this wave's 4 gates; chunk c holds steps [64c, 64c+64)
  const float* xr0 = xpT + (size_t)j * T;
  const float* xr1 = xpT + (size_t)(j + H_DIM) * T;
  const float* xr2 = xpT + (size_t)(j + 2 * H_DIM) * T;
  const float* xr3 = xpT + (size_t)(j + 3 * H_DIM) * T;
  float xc0 = xr0[l], xc1 = xr1[l], xc2 = xr2[l], xc3 = xr3[l];

  float c = 0.0f;

  for (int tc = 0; tc < T; tc += 64) {
    // prefetch next chunk's xp (used 64 steps from now; latency fully hidden)
    const int nx = (tc + 64 < T) ? tc + 64 : tc;
    float xn0 = xr0[nx + l], xn1 = xr1[nx + l];
    float xn2 = xr2[nx + l], xn3 = xr3[nx + l];

    for (int ts = 0; ts < 64; ++ts) {
      const int t = tc + ts;
      float* hb = hl[t & 1];

      if (t == 0) {
        ((float4*)hb)[tid] = make_float4(0.f, 0.f, 0.f, 0.f);  // h_0 = 0
      } else {
        const u64* S = slots + (size_t)(t & 1) * H_DIM;
        unsigned pend = 0xFu;
        while (pend) {
          #pragma unroll
          for (int s = 0; s < 4; ++s) {
            if (pend & (1u << s)) {
              u64 v = __hip_atomic_load(S + tid + 512 * s, __ATOMIC_RELAXED,
                                        __HIP_MEMORY_SCOPE_AGENT);
              if ((unsigned)(v >> 32) == (unsigned)t) {
                union { unsigned u; float f; } cv;
                cv.u = (unsigned)v;
                hb[tid + 512 * s] = cv.f;
                pend &= ~(1u << s);
              }
            }
          }
          if (pend) __builtin_amdgcn_s_sleep(1);
        }
      }
      __syncthreads();

      float acc0 = 0.f, acc1 = 0.f, acc2 = 0.f, acc3 = 0.f;
      #pragma unroll
      for (int k = 0; k < 8; ++k) {
        float4 h4 = ((const float4*)hb)[l + 64 * k];
        acc0 = fmaf(wreg[0 + k * 4 + 0], h4.x, acc0);
        acc0 = fmaf(wreg[0 + k * 4 + 1], h4.y, acc0);
        acc0 = fmaf(wreg[0 + k * 4 + 2], h4.z, acc0);
        acc0 = fmaf(wreg[0 + k * 4 + 3], h4.w, acc0);
        acc1 = fmaf(wreg[32 + k * 4 + 0], h4.x, acc1);
        acc1 = fmaf(wreg[32 + k * 4 + 1], h4.y, acc1);
        acc1 = fmaf(wreg[32 + k * 4 + 2], h4.z, acc1);
        acc1 = fmaf(wreg[32 + k * 4 + 3], h4.w, acc1);
        acc2 = fmaf(wreg[64 + k * 4 + 0], h4.x, acc2);
        acc2 = fmaf(wreg[64 + k * 4 + 1], h4.y, acc2);
        acc2 = fmaf(wreg[64 + k * 4 + 2], h4.z, acc2);
        acc2 = fmaf(wreg[64 + k * 4 + 3], h4.w, acc2);
        acc3 = fmaf(wreg[96 + k * 4 + 0], h4.x, acc3);
        acc3 = fmaf(wreg[96 + k * 4 + 1], h4.y, acc3);
        acc3 = fmaf(wreg[96 + k * 4 + 2], h4.z, acc3);
        acc3 = fmaf(wreg[96 + k * 4 + 3], h4.w, acc3);
      }

      // 64-lane butterfly ALLreduce (every lane ends with the full sums)
      #pragma unroll
      for (int off = 32; off; off >>= 1) {
        acc0 += __shfl_xor(acc0, off);
        acc1 += __shfl_xor(acc1, off);
        acc2 += __shfl_xor(acc2, off);
        acc3 += __shfl_xor(acc3, off);
      }

      // broadcast this step's xp from lane ts; all lanes compute gates
      float xb0 = __shfl(xc0, ts);
      float xb1 = __shfl(xc1, ts);
      float xb2 = __shfl(xc2, ts);
      float xb3 = __shfl(xc3, ts);
      float i_ = sigmoid_f(acc0 + xb0);
      float f_ = sigmoid_f(acc1 + xb1);
      float g_ = tanh_f(acc2 + xb2);
      float o_ = sigmoid_f(acc3 + xb3);
      c = f_ * c + i_ * g_;                 // replicated across lanes
      float h_ = o_ * tanh_f(c);

      if (l == 0) {
        union { float f; unsigned u; } cv;
        cv.f = h_;
        u64 pv = ((u64)(unsigned)(t + 1) << 32) | (u64)cv.u;
        __hip_atomic_store(slots + (size_t)((t + 1) & 1) * H_DIM + j, pv,
                           __ATOMIC_RELAXED, __HIP_MEMORY_SCOPE_AGENT);
        if (ys) ys[(size_t)t * H_DIM + j] = h_;
      }
      // no second sync: hl double-buffer + next step's pre-compute sync
    }
    xc0 = xn0; xc1 = xn1; xc2 = xn2; xc3 = xn3;
  }
}

// ---- fp32 GEMM: CT[n][m] = (A[M][K] @ W[N][K]^T)[m][n] + b0[n] + b1[n] ----
// 128x128 tile, 256 threads, 8x8 microtile, BK=8. Output stored TRANSPOSED
// (N rows, M cols) so the recurrence reads xp coalesced along t.
__global__ __launch_bounds__(256) void gemm_bt_bias_T(
    const float* __restrict__ A, const float* __restrict__ W,
    const float* __restrict__ b0, const float* __restrict__ b1,
    float* __restrict__ CT, int M, int N, int K)
{
  __shared__ float As[8][128];
  __shared__ float Bs[8][128];
  const int tid = threadIdx.x;
  const int n0 = blockIdx.x * 128;
  const int m0 = blockIdx.y * 128;
  const int tx = tid & 15;   // n direction
  const int ty = tid >> 4;   // m direction
  const int lr = tid >> 1;   // loader row 0..127
  const int lk = (tid & 1) * 4;
  const float* Ap = A + (size_t)(m0 + lr) * K + lk;
  const float* Wp = W + (size_t)(n0 + lr) * K + lk;

  float acc[8][8];
  #pragma unroll
  for (int i = 0; i < 8; ++i)
    #pragma unroll
    for (int jj = 0; jj < 8; ++jj) acc[i][jj] = 0.f;

  for (int kt = 0; kt < K; kt += 8) {
    float4 av = *(const float4*)(Ap + kt);
    float4 wv = *(const float4*)(Wp + kt);
    __syncthreads();
    As[lk + 0][lr] = av.x; As[lk + 1][lr] = av.y;
    As[lk + 2][lr] = av.z; As[lk + 3][lr] = av.w;
    Bs[lk + 0][lr] = wv.x; Bs[lk + 1][lr] = wv.y;
    Bs[lk + 2][lr] = wv.z; Bs[lk + 3][lr] = wv.w;
    __syncthreads();
    #pragma unroll
    for (int k = 0; k < 8; ++k) {
      float a[8], b[8];
      *(float4*)&a[0] = *(const float4*)&As[k][ty * 8];
      *(float4*)&a[4] = *(const float4*)&As[k][ty * 8 + 4];
      *(float4*)&b[0] = *(const float4*)&Bs[k][tx * 8];
      *(float4*)&b[4] = *(const float4*)&Bs[k][tx * 8 + 4];
      #pragma unroll
      for (int i = 0; i < 8; ++i)
        #pragma unroll
        for (int jj = 0; jj < 8; ++jj)
          acc[i][jj] = fmaf(a[i], b[jj], acc[i][jj]);
    }
  }

  const int n = n0 + tx * 8;
  const int m = m0 + ty * 8;
  #pragma unroll
  for (int jj = 0; jj < 8; ++jj) {
    float b = b0[n + jj] + (b1 ? b1[n + jj] : 0.f);
    float* crow = CT + (size_t)(n + jj) * M + m;   // transposed: row n, cols m
    float4 v0 = make_float4(acc[0][jj] + b, acc[1][jj] + b,
                            acc[2][jj] + b, acc[3][jj] + b);
    float4 v1 = make_float4(acc[4][jj] + b, acc[5][jj] + b,
                            acc[6][jj] + b, acc[7][jj] + b);
    *(float4*)crow = v0;
    *(float4*)(crow + 4) = v1;
  }
}

// ---- final FC: out[o] = dot(h_last, fc_w[o]) + fc_b[o], one wave/output ----
// h_last read from layer-1 tagged slots (parity 0, tag T), low 32 bits.
__global__ void fc_kernel(const u64* __restrict__ hslots,
                          const float* __restrict__ Wf,
                          const float* __restrict__ bf,
                          float* __restrict__ out)
{
  const int o = blockIdx.x;
  const int l = threadIdx.x;
  const float* wr = Wf + (size_t)o * H_DIM;
  float s = 0.f;
  #pragma unroll
  for (int k = 0; k < 32; ++k) {
    union { unsigned u; float f; } cv;
    cv.u = (unsigned)hslots[l + 64 * k];
    s = fmaf(wr[l + 64 * k], cv.f, s);
  }
  #pragma unroll
  for (int off = 32; off; off >>= 1) s += __shfl_xor(s, off);
  if (l == 0) out[o] = s + bf[o];
}

extern "C" void kernel_launch(void* const* d_in, const int* in_sizes, int n_in,
                              void* d_out, int out_size, void* d_ws, size_t ws_size,
                              hipStream_t stream) {
  const float* x    = (const float*)d_in[0];
  const float* Wih0 = (const float*)d_in[1];
  const float* Whh0 = (const float*)d_in[2];
  const float* bih0 = (const float*)d_in[3];
  const float* bhh0 = (const float*)d_in[4];
  const float* Wih1 = (const float*)d_in[5];
  const float* Whh1 = (const float*)d_in[6];
  const float* bih1 = (const float*)d_in[7];
  const float* bhh1 = (const float*)d_in[8];
  const float* fcw  = (const float*)d_in[9];
  const float* fcb  = (const float*)d_in[10];
  float* out = (float*)d_out;

  // workspace layout (floats): ~84 MB
  float* ws   = (float*)d_ws;
  float* xpT  = ws;                      // (8192, 2048) = 16777216
  float* ys   = ws + 16777216;           // (2048, 2048) =  4194304
  u64* slots0 = (u64*)(ws + 20971520);   // 2 parities x 2048 tagged h (32 KB)
  u64* slots1 = slots0 + 2 * H_DIM;      // layer 1 (separate: fresh poison)

  dim3 gblk(256);
  dim3 ggrid(H4_DIM / 128, T_LEN / 128);  // (64, 16)

  // layer 0: xpT = (x @ Wih0^T + bih0+bhh0)^T; recurrence -> ys
  gemm_bt_bias_T<<<ggrid, gblk, 0, stream>>>(x, Wih0, bih0, bhh0, xpT,
                                             T_LEN, H4_DIM, 512);
  lstm_rec<<<256, 512, 0, stream>>>(Whh0, xpT, slots0, ys, T_LEN);

  // layer 1: xpT = (ys @ Wih1^T + bih1+bhh1)^T; recurrence, keep only h_last
  gemm_bt_bias_T<<<ggrid, gblk, 0, stream>>>(ys, Wih1, bih1, bhh1, xpT,
                                             T_LEN, H4_DIM, H_DIM);
  lstm_rec<<<256, 512, 0, stream>>>(Whh1, xpT, slots1, nullptr, T_LEN);

  // h_last of layer 1: slots1 parity (T&1)=0, tag T
  fc_kernel<<<512, 64, 0, stream>>>(slots1, fcw, fcb, out);
}

// Round 4
// 12496.580 us; speedup vs baseline: 1.2010x; 1.2010x over previous
//
#include <hip/hip_runtime.h>
#include <cstdint>

// Problem constants: D=512, H=2048, T=2048, O=512, 4H=8192.
#define H_DIM 2048
#define H4_DIM 8192
#define T_LEN 2048

typedef unsigned long long u64;
typedef __attribute__((ext_vector_type(2))) float v2f;

__device__ __forceinline__ float sigmoid_f(float x) {
  return 1.0f / (1.0f + __expf(-x));
}
__device__ __forceinline__ float tanh_f(float x) {
  float ax = fabsf(x);
  float e = __expf(-2.0f * ax);
  float r = (1.0f - e) / (1.0f + e);
  return copysignf(r, x);
}

// ---- persistent LSTM recurrence, weights register-resident, NO barrier ----
// Cross-step exchange: slot[parity][j] = (tag<<32)|bits(h_j), relaxed agent
// 64-bit atomics (LLC-coherent, no fences/cache-maintenance). Parity
// double-buffer + all-to-all dependence makes overwrite-before-read
// impossible. 0xAAAAAAAA poison never matches tags 1..2048 -> no init needed.
//
// r4: r2 structure (two syncs, single LDS h buffer, lane-0 scalar xp
// prefetch) + packed-fp32 matvec (v_pk_fma_f32, halves FMA issue on the
// critical path) + tightened poll loop (always-reload, __all wave vote).
__global__ __launch_bounds__(512, 2) void lstm_rec(
    const float* __restrict__ Whh,   // (8192, 2048)
    const float* __restrict__ xp,    // (T, 8192) x-projection + biases
    u64* __restrict__ slots,         // 2 * 2048 tagged h slots
    float* __restrict__ ys,          // (T, 2048) or nullptr
    int T)
{
  __shared__ float hl[H_DIM];
  const int g = blockIdx.x;
  const int tid = threadIdx.x;
  const int w = tid >> 6;
  const int l = tid & 63;
  const int j = g * 8 + w;

  // one-time weight load (each element read exactly once grid-wide),
  // packed as float2 for v_pk_fma_f32
  v2f wreg[64];
  #pragma unroll
  for (int q = 0; q < 4; ++q) {
    const float* wr = Whh + (size_t)(j + q * H_DIM) * H_DIM + l * 4;
    #pragma unroll
    for (int k = 0; k < 8; ++k) {
      float4 v = *(const float4*)(wr + 256 * k);
      v2f lo; lo.x = v.x; lo.y = v.y;
      v2f hi; hi.x = v.z; hi.y = v.w;
      wreg[q * 16 + k * 2 + 0] = lo;
      wreg[q * 16 + k * 2 + 1] = hi;
    }
  }

  float c = 0.0f;

  for (int t = 0; t < T; ++t) {
    // prefetch this step's x-projection early (consumed after the reduce;
    // the poll loop below covers the HBM latency)
    float xq0 = 0.f, xq1 = 0.f, xq2 = 0.f, xq3 = 0.f;
    if (l == 0) {
      const float* xrow = xp + (size_t)t * H4_DIM + j;
      xq0 = xrow[0];
      xq1 = xrow[H_DIM];
      xq2 = xrow[2 * H_DIM];
      xq3 = xrow[3 * H_DIM];
    }

    if (t == 0) {
      ((float4*)hl)[tid] = make_float4(0.f, 0.f, 0.f, 0.f);  // h_0 = 0
    } else {
      // consume h_t: tight poll, always reload all 4 groups, wave vote
      const u64* S = slots + (size_t)(t & 1) * H_DIM + tid;
      u64 v0, v1, v2, v3;
      for (;;) {
        v0 = __hip_atomic_load(S, __ATOMIC_RELAXED, __HIP_MEMORY_SCOPE_AGENT);
        v1 = __hip_atomic_load(S + 512, __ATOMIC_RELAXED, __HIP_MEMORY_SCOPE_AGENT);
        v2 = __hip_atomic_load(S + 1024, __ATOMIC_RELAXED, __HIP_MEMORY_SCOPE_AGENT);
        v3 = __hip_atomic_load(S + 1536, __ATOMIC_RELAXED, __HIP_MEMORY_SCOPE_AGENT);
        bool ok = ((unsigned)(v0 >> 32) == (unsigned)t) &
                  ((unsigned)(v1 >> 32) == (unsigned)t) &
                  ((unsigned)(v2 >> 32) == (unsigned)t) &
                  ((unsigned)(v3 >> 32) == (unsigned)t);
        if (__all(ok)) break;
        __builtin_amdgcn_s_sleep(1);
      }
      hl[tid]        = __uint_as_float((unsigned)v0);
      hl[tid + 512]  = __uint_as_float((unsigned)v1);
      hl[tid + 1024] = __uint_as_float((unsigned)v2);
      hl[tid + 1536] = __uint_as_float((unsigned)v3);
    }
    __syncthreads();

    // packed matvec: 64 v_pk_fma_f32 per thread (4 gates x 16)
    v2f a0 = {0.f, 0.f}, a1 = {0.f, 0.f}, a2 = {0.f, 0.f}, a3 = {0.f, 0.f};
    #pragma unroll
    for (int k = 0; k < 8; ++k) {
      float4 h4 = ((const float4*)hl)[l + 64 * k];
      v2f hlo; hlo.x = h4.x; hlo.y = h4.y;
      v2f hhi; hhi.x = h4.z; hhi.y = h4.w;
      a0 = __builtin_elementwise_fma(wreg[0 + k * 2], hlo, a0);
      a0 = __builtin_elementwise_fma(wreg[1 + k * 2], hhi, a0);
      a1 = __builtin_elementwise_fma(wreg[16 + k * 2], hlo, a1);
      a1 = __builtin_elementwise_fma(wreg[17 + k * 2], hhi, a1);
      a2 = __builtin_elementwise_fma(wreg[32 + k * 2], hlo, a2);
      a2 = __builtin_elementwise_fma(wreg[33 + k * 2], hhi, a2);
      a3 = __builtin_elementwise_fma(wreg[48 + k * 2], hlo, a3);
      a3 = __builtin_elementwise_fma(wreg[49 + k * 2], hhi, a3);
    }
    float acc0 = a0.x + a0.y;
    float acc1 = a1.x + a1.y;
    float acc2 = a2.x + a2.y;
    float acc3 = a3.x + a3.y;

    // 64-lane butterfly reduce (4 gate dots)
    #pragma unroll
    for (int off = 32; off; off >>= 1) {
      acc0 += __shfl_xor(acc0, off);
      acc1 += __shfl_xor(acc1, off);
      acc2 += __shfl_xor(acc2, off);
      acc3 += __shfl_xor(acc3, off);
    }

    if (l == 0) {
      float i_ = sigmoid_f(acc0 + xq0);
      float f_ = sigmoid_f(acc1 + xq1);
      float g_ = tanh_f(acc2 + xq2);
      float o_ = sigmoid_f(acc3 + xq3);
      c = f_ * c + i_ * g_;
      float h_ = o_ * tanh_f(c);
      // publish h_{t+1} ASAP (tagged, single 8B atomic -> LLC)
      union { float f; unsigned u; } cv;
      cv.f = h_;
      u64 pv = ((u64)(unsigned)(t + 1) << 32) | (u64)cv.u;
      __hip_atomic_store(slots + (size_t)((t + 1) & 1) * H_DIM + j, pv,
                         __ATOMIC_RELAXED, __HIP_MEMORY_SCOPE_AGENT);
      if (ys) ys[(size_t)t * H_DIM + j] = h_;
    }
    // all waves must finish reading hl before next step's poll overwrites it
    __syncthreads();
  }
}

// ---- fp32 GEMM: C[M][N] = A[M][K] @ W[N][K]^T + b0[n] + b1[n] ----
// 128x128 tile, 256 threads, 8x8 microtile, BK=8.
__global__ __launch_bounds__(256) void gemm_bt_bias(
    const float* __restrict__ A, const float* __restrict__ W,
    const float* __restrict__ b0, const float* __restrict__ b1,
    float* __restrict__ C, int M, int N, int K)
{
  __shared__ float As[8][128];
  __shared__ float Bs[8][128];
  const int tid = threadIdx.x;
  const int n0 = blockIdx.x * 128;
  const int m0 = blockIdx.y * 128;
  const int tx = tid & 15;   // n direction
  const int ty = tid >> 4;   // m direction
  const int lr = tid >> 1;   // loader row 0..127
  const int lk = (tid & 1) * 4;
  const float* Ap = A + (size_t)(m0 + lr) * K + lk;
  const float* Wp = W + (size_t)(n0 + lr) * K + lk;

  float acc[8][8];
  #pragma unroll
  for (int i = 0; i < 8; ++i)
    #pragma unroll
    for (int jj = 0; jj < 8; ++jj) acc[i][jj] = 0.f;

  for (int kt = 0; kt < K; kt += 8) {
    float4 av = *(const float4*)(Ap + kt);
    float4 wv = *(const float4*)(Wp + kt);
    __syncthreads();
    As[lk + 0][lr] = av.x; As[lk + 1][lr] = av.y;
    As[lk + 2][lr] = av.z; As[lk + 3][lr] = av.w;
    Bs[lk + 0][lr] = wv.x; Bs[lk + 1][lr] = wv.y;
    Bs[lk + 2][lr] = wv.z; Bs[lk + 3][lr] = wv.w;
    __syncthreads();
    #pragma unroll
    for (int k = 0; k < 8; ++k) {
      float a[8], b[8];
      *(float4*)&a[0] = *(const float4*)&As[k][ty * 8];
      *(float4*)&a[4] = *(const float4*)&As[k][ty * 8 + 4];
      *(float4*)&b[0] = *(const float4*)&Bs[k][tx * 8];
      *(float4*)&b[4] = *(const float4*)&Bs[k][tx * 8 + 4];
      #pragma unroll
      for (int i = 0; i < 8; ++i)
        #pragma unroll
        for (int jj = 0; jj < 8; ++jj)
          acc[i][jj] = fmaf(a[i], b[jj], acc[i][jj]);
    }
  }

  const int n = n0 + tx * 8;
  float bias[8];
  #pragma unroll
  for (int jj = 0; jj < 8; ++jj)
    bias[jj] = b0[n + jj] + (b1 ? b1[n + jj] : 0.f);
  #pragma unroll
  for (int i = 0; i < 8; ++i) {
    float* crow = C + (size_t)(m0 + ty * 8 + i) * N + n;
    float4 v0 = make_float4(acc[i][0] + bias[0], acc[i][1] + bias[1],
                            acc[i][2] + bias[2], acc[i][3] + bias[3]);
    float4 v1 = make_float4(acc[i][4] + bias[4], acc[i][5] + bias[5],
                            acc[i][6] + bias[6], acc[i][7] + bias[7]);
    *(float4*)crow = v0;
    *(float4*)(crow + 4) = v1;
  }
}

// ---- final FC: out[o] = dot(h_last, fc_w[o]) + fc_b[o], one wave/output ----
// h_last read from layer-1 tagged slots (parity 0, tag T), low 32 bits.
__global__ void fc_kernel(const u64* __restrict__ hslots,
                          const float* __restrict__ Wf,
                          const float* __restrict__ bf,
                          float* __restrict__ out)
{
  const int o = blockIdx.x;
  const int l = threadIdx.x;
  const float* wr = Wf + (size_t)o * H_DIM;
  float s = 0.f;
  #pragma unroll
  for (int k = 0; k < 32; ++k) {
    union { unsigned u; float f; } cv;
    cv.u = (unsigned)hslots[l + 64 * k];
    s = fmaf(wr[l + 64 * k], cv.f, s);
  }
  #pragma unroll
  for (int off = 32; off; off >>= 1) s += __shfl_xor(s, off);
  if (l == 0) out[o] = s + bf[o];
}

extern "C" void kernel_launch(void* const* d_in, const int* in_sizes, int n_in,
                              void* d_out, int out_size, void* d_ws, size_t ws_size,
                              hipStream_t stream) {
  const float* x    = (const float*)d_in[0];
  const float* Wih0 = (const float*)d_in[1];
  const float* Whh0 = (const float*)d_in[2];
  const float* bih0 = (const float*)d_in[3];
  const float* bhh0 = (const float*)d_in[4];
  const float* Wih1 = (const float*)d_in[5];
  const float* Whh1 = (const float*)d_in[6];
  const float* bih1 = (const float*)d_in[7];
  const float* bhh1 = (const float*)d_in[8];
  const float* fcw  = (const float*)d_in[9];
  const float* fcb  = (const float*)d_in[10];
  float* out = (float*)d_out;

  // workspace layout (floats): ~84 MB
  float* ws   = (float*)d_ws;
  float* xp   = ws;                      // (2048, 8192) = 16777216
  float* ys   = ws + 16777216;           // (2048, 2048) =  4194304
  u64* slots0 = (u64*)(ws + 20971520);   // 2 parities x 2048 tagged h (32 KB)
  u64* slots1 = slots0 + 2 * H_DIM;      // layer 1 (separate: fresh poison)

  dim3 gblk(256);
  dim3 ggrid(H4_DIM / 128, T_LEN / 128);  // (64, 16)

  // layer 0: xp = x @ Wih0^T + (bih0+bhh0); recurrence -> ys
  gemm_bt_bias<<<ggrid, gblk, 0, stream>>>(x, Wih0, bih0, bhh0, xp,
                                           T_LEN, H4_DIM, 512);
  lstm_rec<<<256, 512, 0, stream>>>(Whh0, xp, slots0, ys, T_LEN);

  // layer 1: xp = ys @ Wih1^T + (bih1+bhh1); recurrence, keep only h_last
  gemm_bt_bias<<<ggrid, gblk, 0, stream>>>(ys, Wih1, bih1, bhh1, xp,
                                           T_LEN, H4_DIM, H_DIM);
  lstm_rec<<<256, 512, 0, stream>>>(Whh1, xp, slots1, nullptr, T_LEN);

  // h_last of layer 1: slots1 parity (T&1)=0, tag T
  fc_kernel<<<512, 64, 0, stream>>>(slots1, fcw, fcb, out);
}

// Round 5
// 11234.750 us; speedup vs baseline: 1.3359x; 1.1123x over previous
//
#include <hip/hip_runtime.h>
#include <cstdint>

// Problem constants: D=512, H=2048, T=2048, O=512, 4H=8192.
#define H_DIM 2048
#define H4_DIM 8192
#define T_LEN 2048
#define NREP 8           // slot replicas (per-XCD contention spreading)

typedef unsigned long long u64;
typedef __attribute__((ext_vector_type(2))) float v2f;

__device__ __forceinline__ float sigmoid_f(float x) {
  return 1.0f / (1.0f + __expf(-x));
}
__device__ __forceinline__ float tanh_f(float x) {
  float ax = fabsf(x);
  float e = __expf(-2.0f * ax);
  float r = (1.0f - e) / (1.0f + e);
  return copysignf(r, x);
}

// ---- persistent LSTM recurrence, weights register-resident, NO barrier ----
// Cross-step exchange: slot[rep][parity][j] = (tag<<32)|bits(h_j), relaxed
// agent 64-bit atomics. r5: slots replicated 8x; producers (lanes 0..7 of
// each wave, identical replicated gate math) store h to all 8 replicas;
// consumers poll only replica blockIdx&7 -> per-line reader fan-in drops
// 256 -> 32 (LLC decontention; %8 matches XCD round-robin dispatch).
// Parity double-buffer + all-to-all dependence still forbids
// overwrite-before-read; 0xAAAAAAAA poison never matches tags 1..2048.
__global__ __launch_bounds__(512, 2) void lstm_rec(
    const float* __restrict__ Whh,   // (8192, 2048)
    const float* __restrict__ xp,    // (T, 8192) x-projection + biases
    u64* __restrict__ slots,         // NREP * 2 * 2048 tagged h slots
    float* __restrict__ ys,          // (T, 2048) or nullptr
    int T)
{
  __shared__ float hl[H_DIM];
  const int g = blockIdx.x;
  const int tid = threadIdx.x;
  const int w = tid >> 6;
  const int l = tid & 63;
  const int j = g * 8 + w;
  const int rep = g & (NREP - 1);

  // one-time weight load (each element read exactly once grid-wide),
  // packed as float2 for v_pk_fma_f32
  v2f wreg[64];
  #pragma unroll
  for (int q = 0; q < 4; ++q) {
    const float* wr = Whh + (size_t)(j + q * H_DIM) * H_DIM + l * 4;
    #pragma unroll
    for (int k = 0; k < 8; ++k) {
      float4 v = *(const float4*)(wr + 256 * k);
      v2f lo; lo.x = v.x; lo.y = v.y;
      v2f hi; hi.x = v.z; hi.y = v.w;
      wreg[q * 16 + k * 2 + 0] = lo;
      wreg[q * 16 + k * 2 + 1] = hi;
    }
  }

  float c = 0.0f;

  for (int t = 0; t < T; ++t) {
    // prefetch this step's x-projection early (lanes 0..7, same 4 addresses:
    // broadcast lines; consumed after the reduce by the 8 publisher lanes)
    float xq0 = 0.f, xq1 = 0.f, xq2 = 0.f, xq3 = 0.f;
    if (l < NREP) {
      const float* xrow = xp + (size_t)t * H4_DIM + j;
      xq0 = xrow[0];
      xq1 = xrow[H_DIM];
      xq2 = xrow[2 * H_DIM];
      xq3 = xrow[3 * H_DIM];
    }

    if (t == 0) {
      ((float4*)hl)[tid] = make_float4(0.f, 0.f, 0.f, 0.f);  // h_0 = 0
    } else {
      // consume h_t from my replica: tight poll, wave vote
      const u64* S = slots + ((size_t)(rep * 2 + (t & 1))) * H_DIM + tid;
      u64 v0, v1, v2, v3;
      for (;;) {
        v0 = __hip_atomic_load(S, __ATOMIC_RELAXED, __HIP_MEMORY_SCOPE_AGENT);
        v1 = __hip_atomic_load(S + 512, __ATOMIC_RELAXED, __HIP_MEMORY_SCOPE_AGENT);
        v2 = __hip_atomic_load(S + 1024, __ATOMIC_RELAXED, __HIP_MEMORY_SCOPE_AGENT);
        v3 = __hip_atomic_load(S + 1536, __ATOMIC_RELAXED, __HIP_MEMORY_SCOPE_AGENT);
        bool ok = ((unsigned)(v0 >> 32) == (unsigned)t) &
                  ((unsigned)(v1 >> 32) == (unsigned)t) &
                  ((unsigned)(v2 >> 32) == (unsigned)t) &
                  ((unsigned)(v3 >> 32) == (unsigned)t);
        if (__all(ok)) break;
        __builtin_amdgcn_s_sleep(1);
      }
      hl[tid]        = __uint_as_float((unsigned)v0);
      hl[tid + 512]  = __uint_as_float((unsigned)v1);
      hl[tid + 1024] = __uint_as_float((unsigned)v2);
      hl[tid + 1536] = __uint_as_float((unsigned)v3);
    }
    __syncthreads();

    // packed matvec: 64 v_pk_fma_f32 per thread (4 gates x 16)
    v2f a0 = {0.f, 0.f}, a1 = {0.f, 0.f}, a2 = {0.f, 0.f}, a3 = {0.f, 0.f};
    #pragma unroll
    for (int k = 0; k < 8; ++k) {
      float4 h4 = ((const float4*)hl)[l + 64 * k];
      v2f hlo; hlo.x = h4.x; hlo.y = h4.y;
      v2f hhi; hhi.x = h4.z; hhi.y = h4.w;
      a0 = __builtin_elementwise_fma(wreg[0 + k * 2], hlo, a0);
      a0 = __builtin_elementwise_fma(wreg[1 + k * 2], hhi, a0);
      a1 = __builtin_elementwise_fma(wreg[16 + k * 2], hlo, a1);
      a1 = __builtin_elementwise_fma(wreg[17 + k * 2], hhi, a1);
      a2 = __builtin_elementwise_fma(wreg[32 + k * 2], hlo, a2);
      a2 = __builtin_elementwise_fma(wreg[33 + k * 2], hhi, a2);
      a3 = __builtin_elementwise_fma(wreg[48 + k * 2], hlo, a3);
      a3 = __builtin_elementwise_fma(wreg[49 + k * 2], hhi, a3);
    }
    float acc0 = a0.x + a0.y;
    float acc1 = a1.x + a1.y;
    float acc2 = a2.x + a2.y;
    float acc3 = a3.x + a3.y;

    // 64-lane butterfly ALLreduce (every lane ends with the full 4 dots)
    #pragma unroll
    for (int off = 32; off; off >>= 1) {
      acc0 += __shfl_xor(acc0, off);
      acc1 += __shfl_xor(acc1, off);
      acc2 += __shfl_xor(acc2, off);
      acc3 += __shfl_xor(acc3, off);
    }

    // gates on all lanes (replicated, bit-identical on lanes 0..7 which hold
    // real xq); lane k<8 publishes to replica k; lane 0 writes ys
    float i_ = sigmoid_f(acc0 + xq0);
    float f_ = sigmoid_f(acc1 + xq1);
    float g_ = tanh_f(acc2 + xq2);
    float o_ = sigmoid_f(acc3 + xq3);
    c = f_ * c + i_ * g_;
    float h_ = o_ * tanh_f(c);

    if (l < NREP) {
      union { float f; unsigned u; } cv;
      cv.f = h_;
      u64 pv = ((u64)(unsigned)(t + 1) << 32) | (u64)cv.u;
      __hip_atomic_store(
          slots + ((size_t)(l * 2 + ((t + 1) & 1))) * H_DIM + j, pv,
          __ATOMIC_RELAXED, __HIP_MEMORY_SCOPE_AGENT);
      if (l == 0 && ys) ys[(size_t)t * H_DIM + j] = h_;
    }
    // all waves must finish reading hl before next step's poll overwrites it
    __syncthreads();
  }
}

// ---- fp32 GEMM: C[M][N] = A[M][K] @ W[N][K]^T + b0[n] + b1[n] ----
// 128x128 tile, 256 threads, 8x8 microtile, BK=8.
__global__ __launch_bounds__(256) void gemm_bt_bias(
    const float* __restrict__ A, const float* __restrict__ W,
    const float* __restrict__ b0, const float* __restrict__ b1,
    float* __restrict__ C, int M, int N, int K)
{
  __shared__ float As[8][128];
  __shared__ float Bs[8][128];
  const int tid = threadIdx.x;
  const int n0 = blockIdx.x * 128;
  const int m0 = blockIdx.y * 128;
  const int tx = tid & 15;   // n direction
  const int ty = tid >> 4;   // m direction
  const int lr = tid >> 1;   // loader row 0..127
  const int lk = (tid & 1) * 4;
  const float* Ap = A + (size_t)(m0 + lr) * K + lk;
  const float* Wp = W + (size_t)(n0 + lr) * K + lk;

  float acc[8][8];
  #pragma unroll
  for (int i = 0; i < 8; ++i)
    #pragma unroll
    for (int jj = 0; jj < 8; ++jj) acc[i][jj] = 0.f;

  for (int kt = 0; kt < K; kt += 8) {
    float4 av = *(const float4*)(Ap + kt);
    float4 wv = *(const float4*)(Wp + kt);
    __syncthreads();
    As[lk + 0][lr] = av.x; As[lk + 1][lr] = av.y;
    As[lk + 2][lr] = av.z; As[lk + 3][lr] = av.w;
    Bs[lk + 0][lr] = wv.x; Bs[lk + 1][lr] = wv.y;
    Bs[lk + 2][lr] = wv.z; Bs[lk + 3][lr] = wv.w;
    __syncthreads();
    #pragma unroll
    for (int k = 0; k < 8; ++k) {
      float a[8], b[8];
      *(float4*)&a[0] = *(const float4*)&As[k][ty * 8];
      *(float4*)&a[4] = *(const float4*)&As[k][ty * 8 + 4];
      *(float4*)&b[0] = *(const float4*)&Bs[k][tx * 8];
      *(float4*)&b[4] = *(const float4*)&Bs[k][tx * 8 + 4];
      #pragma unroll
      for (int i = 0; i < 8; ++i)
        #pragma unroll
        for (int jj = 0; jj < 8; ++jj)
          acc[i][jj] = fmaf(a[i], b[jj], acc[i][jj]);
    }
  }

  const int n = n0 + tx * 8;
  float bias[8];
  #pragma unroll
  for (int jj = 0; jj < 8; ++jj)
    bias[jj] = b0[n + jj] + (b1 ? b1[n + jj] : 0.f);
  #pragma unroll
  for (int i = 0; i < 8; ++i) {
    float* crow = C + (size_t)(m0 + ty * 8 + i) * N + n;
    float4 v0 = make_float4(acc[i][0] + bias[0], acc[i][1] + bias[1],
                            acc[i][2] + bias[2], acc[i][3] + bias[3]);
    float4 v1 = make_float4(acc[i][4] + bias[4], acc[i][5] + bias[5],
                            acc[i][6] + bias[6], acc[i][7] + bias[7]);
    *(float4*)crow = v0;
    *(float4*)(crow + 4) = v1;
  }
}

// ---- final FC: out[o] = dot(h_last, fc_w[o]) + fc_b[o], one wave/output ----
// h_last read from layer-1 tagged slots, replica 0, parity 0 (tag T).
__global__ void fc_kernel(const u64* __restrict__ hslots,
                          const float* __restrict__ Wf,
                          const float* __restrict__ bf,
                          float* __restrict__ out)
{
  const int o = blockIdx.x;
  const int l = threadIdx.x;
  const float* wr = Wf + (size_t)o * H_DIM;
  float s = 0.f;
  #pragma unroll
  for (int k = 0; k < 32; ++k) {
    union { unsigned u; float f; } cv;
    cv.u = (unsigned)hslots[l + 64 * k];
    s = fmaf(wr[l + 64 * k], cv.f, s);
  }
  #pragma unroll
  for (int off = 32; off; off >>= 1) s += __shfl_xor(s, off);
  if (l == 0) out[o] = s + bf[o];
}

extern "C" void kernel_launch(void* const* d_in, const int* in_sizes, int n_in,
                              void* d_out, int out_size, void* d_ws, size_t ws_size,
                              hipStream_t stream) {
  const float* x    = (const float*)d_in[0];
  const float* Wih0 = (const float*)d_in[1];
  const float* Whh0 = (const float*)d_in[2];
  const float* bih0 = (const float*)d_in[3];
  const float* bhh0 = (const float*)d_in[4];
  const float* Wih1 = (const float*)d_in[5];
  const float* Whh1 = (const float*)d_in[6];
  const float* bih1 = (const float*)d_in[7];
  const float* bhh1 = (const float*)d_in[8];
  const float* fcw  = (const float*)d_in[9];
  const float* fcb  = (const float*)d_in[10];
  float* out = (float*)d_out;

  // workspace layout (floats): ~85 MB
  float* ws   = (float*)d_ws;
  float* xp   = ws;                      // (2048, 8192) = 16777216
  float* ys   = ws + 16777216;           // (2048, 2048) =  4194304
  u64* slots0 = (u64*)(ws + 20971520);   // NREP x 2 x 2048 tagged h (256 KB)
  u64* slots1 = slots0 + NREP * 2 * H_DIM;  // layer 1 (fresh poison)

  dim3 gblk(256);
  dim3 ggrid(H4_DIM / 128, T_LEN / 128);  // (64, 16)

  // layer 0: xp = x @ Wih0^T + (bih0+bhh0); recurrence -> ys
  gemm_bt_bias<<<ggrid, gblk, 0, stream>>>(x, Wih0, bih0, bhh0, xp,
                                           T_LEN, H4_DIM, 512);
  lstm_rec<<<256, 512, 0, stream>>>(Whh0, xp, slots0, ys, T_LEN);

  // layer 1: xp = ys @ Wih1^T + (bih1+bhh1); recurrence, keep only h_last
  gemm_bt_bias<<<ggrid, gblk, 0, stream>>>(ys, Wih1, bih1, bhh1, xp,
                                           T_LEN, H4_DIM, H_DIM);
  lstm_rec<<<256, 512, 0, stream>>>(Whh1, xp, slots1, nullptr, T_LEN);

  // h_last of layer 1: slots1 replica 0, parity (T&1)=0, tag T
  fc_kernel<<<512, 64, 0, stream>>>(slots1, fcw, fcb, out);
}